// Round 5
// baseline (365.409 us; speedup 1.0000x reference)
//
#include <hip/hip_runtime.h>

// ToDenseBEVConvolution R16 — 3 dispatches. R15 confirmed the K2 LDS-atomic
// storm was R13/R14's regression (445->358 fixing it). R13-vs-R14 A/B showed
// the inline chain-walk dense costs only ~+6us vs a separate accum node
// (+5us kernel +12-24us boundary) -> 3-node layout with walk-in-dense is net
// -11..-23us. R16 = R15 K1/K2 (atomic-free prologue) + accum deleted +
// R13's walk-dense verbatim. K2's 16-barrier Hillis-Steele scan replaced by
// a barrier-free __shfl_up wave scan + 2 barriers (same sc[] result).
// Sum order per cell = owner, then chain in push-reverse order = R13's
// (absmax 0.0 there).
//  K1 bev_sort:  zero head inline + deterministic per-block histograms
//                (blkhist) + block-segmented sorted. Nothing needs memset.
//  K2 bev_point: atomic-free bin totals ([seg][bin] psum), shfl-scan prefix,
//                binary-search ranks, LDS-kernel matmul, chain push.
//  K3 bev_dense_row: branch-free level-1 (4 f + 4 nxt loads in flight),
//                rare >=2 collision chains folded in an exec-masked loop.
// NOTE: assumes nblk=(N+255)/256 <= 256 (N <= 65536; harness N=40000).

#define CIN    64
#define COUT   128
#define BEVH   512
#define BEVW   512
#define HW     (BEVH * BEVW)     // 2^18
#define NBINS  16
#define PTS_PER_WAVE  8
#define PTS_PER_BLOCK 32

// ---------------- K1: zero head + deterministic per-block bucket
__global__ __launch_bounds__(256) void bev_sort(
    const int* __restrict__ coords,   // [N,4]
    const int* __restrict__ stride_p,
    int*       __restrict__ head,     // [ncells] -> zeroed here
    int*       __restrict__ blkhist,  // [nblk,16]
    int*       __restrict__ sorted,   // [16, nblk*256] block-segmented
    int n, int nblk, int scap, int ncells)
{
    __shared__ int hist[NBINS];
    const int tid = threadIdx.x;
    const int vb  = blockIdx.x;

    // zero head (2MB over nblk*256 threads, int4 grid-stride)
    {
        int4* h4 = (int4*)head;
        const int tot4 = ncells >> 2;
        const int zero_stride = nblk * 256;
        for (int i = vb * 256 + tid; i < tot4; i += zero_stride)
            h4[i] = make_int4(0, 0, 0, 0);
    }

    if (tid < NBINS) hist[tid] = 0;
    __syncthreads();

    const int i = vb * 256 + tid;
    int k = 0, rank = 0;
    if (i < n) {
        k = coords[i * 4 + 1] / stride_p[0];
        rank = atomicAdd(&hist[k], 1);        // LDS atomic: block-local rank
    }
    __syncthreads();
    if (i < n)
        sorted[k * scap + vb * 256 + rank] = i;
    if (tid < NBINS)
        blkhist[vb * NBINS + tid] = hist[tid];
}

// ---------------- K2: exact-chunk binned matmul, kern[bin] in LDS
__global__ __launch_bounds__(256) void bev_point(
    const int*   __restrict__ coords,
    const float* __restrict__ feats,    // [N,64]
    const float* __restrict__ kern,     // [16,64,128]
    const int*   __restrict__ stride_p,
    const int*   __restrict__ blkhist,  // [nblk,16]
    const int*   __restrict__ sorted,   // [16, scap]
    float*       __restrict__ f,        // [N,128]
    int*         __restrict__ head,     // [ncells] zeroed; stores pt+1
    int*         __restrict__ nxt,      // [N]; 0 = end-of-chain
    int n, int nblk, int scap)
{
    __shared__ float lk[CIN * COUT];    // 32 KB: kern[bin]
    __shared__ int psum[256];           // [seg][bin] partial sums (atomic-free)
    __shared__ int sc[256];             // inclusive prefix of my bin's column
    __shared__ int wsum[4];             // per-wave scan totals
    __shared__ int tot[NBINS];
    __shared__ int cbase[NBINS + 1];    // chunk-count prefix over bins

    const int tid  = threadIdx.x;
    const int wave = tid >> 6;
    const int lane = tid & 63;

    // bin totals WITHOUT LDS atomics: thread t sums rows of column (t&15);
    // then 16 threads fold 16 independent partials each.
    {
        const int bin16 = tid & 15;
        const int seg   = tid >> 4;
        const int per   = (nblk + 15) >> 4;
        const int rlo   = seg * per;
        int rhi = rlo + per; if (rhi > nblk) rhi = nblk;
        int s = 0;
        for (int vb = rlo; vb < rhi; ++vb) s += blkhist[vb * NBINS + bin16];
        psum[tid] = s;
    }
    __syncthreads();
    if (tid < NBINS) {
        int s = 0;
#pragma unroll
        for (int g = 0; g < 16; ++g) s += psum[g * 16 + tid];  // independent reads
        tot[tid] = s;
    }
    __syncthreads();
    if (tid == 0) {
        int acc = 0;
        cbase[0] = 0;
        for (int k = 0; k < NBINS; ++k) {
            acc += (tot[k] + PTS_PER_BLOCK - 1) / PTS_PER_BLOCK;
            cbase[k + 1] = acc;
        }
    }
    __syncthreads();

    const int c = blockIdx.x;
    if (c >= cbase[NBINS]) return;            // block-uniform: safe

    int bin = 0;
    while (cbase[bin + 1] <= c) ++bin;        // uniform 16-entry scan
    const int chunk = c - cbase[bin];
    const int cnt   = tot[bin];

    // inclusive prefix over my bin's per-block counts: barrier-free wave scan
    // (__shfl_up, 6 steps) + cross-wave offset fold (2 barriers total)
    {
        int v = (tid < nblk) ? blkhist[tid * NBINS + bin] : 0;
#pragma unroll
        for (int off = 1; off < 64; off <<= 1) {
            const int t = __shfl_up(v, (unsigned)off, 64);
            if (lane >= off) v += t;
        }
        if (lane == 63) wsum[wave] = v;
        __syncthreads();
        int add = 0;
#pragma unroll
        for (int w = 0; w < 3; ++w)
            if (w < wave) add += wsum[w];
        sc[tid] = v + add;
        __syncthreads();
    }

    // stage kern[bin] -> LDS (256 thr x 8 float4)
    {
        const float4* src = (const float4*)(kern + (size_t)bin * CIN * COUT);
        float4* dst = (float4*)lk;
#pragma unroll
        for (int j = 0; j < 8; ++j)
            dst[j * 256 + tid] = src[j * 256 + tid];
    }
    __syncthreads();

    const int r0 = chunk * PTS_PER_BLOCK + wave * PTS_PER_WAVE;
    const int navail = cnt - r0;
    if (navail <= 0) return;                  // no barrier after this point
    const int np = navail < PTS_PER_WAVE ? navail : PTS_PER_WAVE;

    int pts[PTS_PER_WAVE];
#pragma unroll
    for (int p = 0; p < PTS_PER_WAVE; ++p) {
        const int rr = (p < np) ? (r0 + p) : r0;   // pad tail with p0 (discarded)
        // rank -> (vb, local) via binary search on inclusive prefix (uniform)
        int lo = 0, hi = nblk;
        while (lo < hi) {
            const int mid = (lo + hi) >> 1;
            if (sc[mid] > rr) hi = mid; else lo = mid + 1;
        }
        const int local = rr - (lo ? sc[lo - 1] : 0);
        pts[p] = __builtin_amdgcn_readfirstlane(sorted[bin * scap + lo * 256 + local]);
    }

    float ax[PTS_PER_WAVE], ay[PTS_PER_WAVE];
#pragma unroll
    for (int p = 0; p < PTS_PER_WAVE; ++p) { ax[p] = 0.f; ay[p] = 0.f; }

#pragma unroll
    for (int cc = 0; cc < CIN; ++cc) {
        const float2 kv = *(const float2*)&lk[cc * COUT + 2 * lane];
#pragma unroll
        for (int p = 0; p < PTS_PER_WAVE; ++p) {
            const float fv = feats[(size_t)pts[p] * CIN + cc];  // wave-uniform -> s_load
            ax[p] = fmaf(fv, kv.x, ax[p]);
            ay[p] = fmaf(fv, kv.y, ay[p]);
        }
    }

#pragma unroll
    for (int p = 0; p < PTS_PER_WAVE; ++p) {
        if (p < np)
            *(float2*)(f + (size_t)pts[p] * COUT + 2 * lane) = make_float2(ax[p], ay[p]);
    }

    if (lane == 0) {
        const int stride = stride_p[0];
        for (int p = 0; p < np; ++p) {
            const int pt = pts[p];
            const int cx = coords[pt * 4 + 0];
            const int cz = coords[pt * 4 + 2];
            const int cb = coords[pt * 4 + 3];
            const int cell = (cb << 18) + ((cx / stride) << 9) + (cz / stride);
            const int old = atomicExch(&head[cell], pt + 1);   // lock-free push
            nxt[pt] = old;                                     // 0 = end
        }
    }
}

// ---------------- K3: wave-per-row dense output, chain-fold inlined (R13)
__global__ __launch_bounds__(256) void bev_dense_row(
    const float* __restrict__ f,        // [N,128]
    const int*   __restrict__ head,     // [ncells], pt+1 or 0
    const int*   __restrict__ nxt,      // [N]; 0 = end
    float*       __restrict__ out,      // [B,128,512,512]
    int nrows)                          // B*COUT*BEVH
{
    const int wave = threadIdx.x >> 6;
    const int lane = threadIdx.x & 63;
    const int row = blockIdx.x * 4 + wave;      // row = (b<<16)|(o<<9)|x
    if (row >= nrows) return;

    const int x = row & 511;
    const int o = (row >> 9) & 127;             // wave-uniform
    const int b = row >> 16;                    // wave-uniform
    const int* hrow = head + (b << 18) + (x << 9);   // 2KB contiguous head row
    float* const orow = out + (size_t)row * 512;

#pragma unroll
    for (int h = 0; h < 2; ++h) {
        const int z = h * 256 + lane * 4;
        const int4 h4 = *(const int4*)(hrow + z);    // coalesced 1KB/wave
        float4 v = make_float4(0.f, 0.f, 0.f, 0.f);
        int p0 = h4.x, p1 = h4.y, p2 = h4.z, p3 = h4.w;
        // level 1: owner f-loads and nxt-loads all independent (8 in flight)
        if (p0) { v.x = f[(size_t)(p0 - 1) * COUT + o]; p0 = nxt[p0 - 1]; }
        if (p1) { v.y = f[(size_t)(p1 - 1) * COUT + o]; p1 = nxt[p1 - 1]; }
        if (p2) { v.z = f[(size_t)(p2 - 1) * COUT + o]; p2 = nxt[p2 - 1]; }
        if (p3) { v.w = f[(size_t)(p3 - 1) * COUT + o]; p3 = nxt[p3 - 1]; }
        // rare collision chains (~4% of occupied cells), exec-masked
        while (p0 | p1 | p2 | p3) {
            if (p0) { v.x += f[(size_t)(p0 - 1) * COUT + o]; p0 = nxt[p0 - 1]; }
            if (p1) { v.y += f[(size_t)(p1 - 1) * COUT + o]; p1 = nxt[p1 - 1]; }
            if (p2) { v.z += f[(size_t)(p2 - 1) * COUT + o]; p2 = nxt[p2 - 1]; }
            if (p3) { v.w += f[(size_t)(p3 - 1) * COUT + o]; p3 = nxt[p3 - 1]; }
        }
        *(float4*)(orow + z) = v;                    // coalesced 1KB/wave store
    }
}

// ------------------------------------------------------------------- launch
extern "C" void kernel_launch(void* const* d_in, const int* in_sizes, int n_in,
                              void* d_out, int out_size, void* d_ws, size_t ws_size,
                              hipStream_t stream) {
    const int*   coords   = (const int*)d_in[0];
    const float* feats    = (const float*)d_in[1];
    const float* kern     = (const float*)d_in[2];
    const int*   stride_p = (const int*)d_in[3];
    float* out = (float*)d_out;

    const int n      = in_sizes[0] / 4;      // coords is [N,4]
    const int ncells = out_size / COUT;      // B*H*W = 524288
    const int nblk   = (n + 255) / 256;      // sort blocks (157; must be <=256)
    const int scap   = nblk * 256;           // per-bin segment capacity

    // Workspace: f | head | nxt | blkhist | sorted   (nothing needs memset)
    size_t off = 0;
    float* f      = (float*)((char*)d_ws + off); off += (size_t)n * COUT * sizeof(float);
    int* head     = (int*)((char*)d_ws + off);   off += (size_t)ncells * sizeof(int);
    int* nxt      = (int*)((char*)d_ws + off);   off += (size_t)n * sizeof(int);
    int* blkhist  = (int*)((char*)d_ws + off);   off += (size_t)nblk * NBINS * sizeof(int);
    int* sorted   = (int*)((char*)d_ws + off);   off += (size_t)NBINS * scap * sizeof(int);

    // K1: zero head + bucket (head zeroing ordered before K2 by dispatch order)
    bev_sort<<<nblk, 256, 0, stream>>>(coords, stride_p, head, blkhist, sorted,
                                       n, nblk, scap, ncells);

    // K2: exact chunk count (worst case: every bin has a remainder chunk)
    const int max_chunks = (n + PTS_PER_BLOCK - 1) / PTS_PER_BLOCK + NBINS;
    bev_point<<<max_chunks, 256, 0, stream>>>(coords, feats, kern, stride_p,
                                              blkhist, sorted, f, head, nxt,
                                              n, nblk, scap);

    // K3: dense output with inline chain-fold
    const int nrows = out_size / 512;        // B*COUT*BEVH = 131072
    bev_dense_row<<<nrows / 4, 256, 0, stream>>>(f, head, nxt, out, nrows);
}

// Round 6
// 365.099 us; speedup vs baseline: 1.0008x; 1.0008x over previous
//
#include <hip/hip_runtime.h>

// ToDenseBEVConvolution R17 — R15 (best new-lineage: 4 nodes, branch-free
// dense + accum; 357.8us) with ONLY dense changed. Both A/B pairs (R13->R14
// -5.8, R15->R16 +7.6) prove walk-in-dense costs ~18us > the ~12us boundary
// it saves -> keep accum. Remaining target: dense's f-read pattern. Old
// mapping (o outermost) reads 4B/64B-line per scattered f load with a full
// x-sweep reuse distance -> up to 16x f over-fetch if L2 misses. New dense:
// block = (b, x, og16); wave w owns o = og*16+w*4..+3. Per segment: one int4
// head read (reused across 4 rows), one scattered float4 f load per occupied
// cell (block's 4 waves consume the full 64B line), register transpose, four
// coalesced float4 stores. 4x fewer scattered loads, 4x fewer head reads,
// f-line reuse intra-block.
//  K1 bev_sort:  zero head inline + per-block histograms + segmented sorted.
//  K2 bev_point: atomic-free bin totals, shfl-scan prefix, binary-search
//                ranks, LDS-kernel matmul, chain push (R15 verbatim).
//  K3 bev_accum: owner folds collision chain in-place (R11 D4 verbatim).
//  K4 bev_dense_o16: o-grouped dense as above.
// NOTE: assumes nblk=(N+255)/256 <= 256 (N <= 65536; harness N=40000).

#define CIN    64
#define COUT   128
#define BEVH   512
#define BEVW   512
#define HW     (BEVH * BEVW)     // 2^18
#define NBINS  16
#define PTS_PER_WAVE  8
#define PTS_PER_BLOCK 32

// ---------------- K1: zero head + deterministic per-block bucket
__global__ __launch_bounds__(256) void bev_sort(
    const int* __restrict__ coords,   // [N,4]
    const int* __restrict__ stride_p,
    int*       __restrict__ head,     // [ncells] -> zeroed here
    int*       __restrict__ blkhist,  // [nblk,16]
    int*       __restrict__ sorted,   // [16, nblk*256] block-segmented
    int n, int nblk, int scap, int ncells)
{
    __shared__ int hist[NBINS];
    const int tid = threadIdx.x;
    const int vb  = blockIdx.x;

    // zero head (2MB over nblk*256 threads, int4 grid-stride)
    {
        int4* h4 = (int4*)head;
        const int tot4 = ncells >> 2;
        const int zero_stride = nblk * 256;
        for (int i = vb * 256 + tid; i < tot4; i += zero_stride)
            h4[i] = make_int4(0, 0, 0, 0);
    }

    if (tid < NBINS) hist[tid] = 0;
    __syncthreads();

    const int i = vb * 256 + tid;
    int k = 0, rank = 0;
    if (i < n) {
        k = coords[i * 4 + 1] / stride_p[0];
        rank = atomicAdd(&hist[k], 1);        // LDS atomic: block-local rank
    }
    __syncthreads();
    if (i < n)
        sorted[k * scap + vb * 256 + rank] = i;
    if (tid < NBINS)
        blkhist[vb * NBINS + tid] = hist[tid];
}

// ---------------- K2: exact-chunk binned matmul, kern[bin] in LDS
__global__ __launch_bounds__(256) void bev_point(
    const int*   __restrict__ coords,
    const float* __restrict__ feats,    // [N,64]
    const float* __restrict__ kern,     // [16,64,128]
    const int*   __restrict__ stride_p,
    const int*   __restrict__ blkhist,  // [nblk,16]
    const int*   __restrict__ sorted,   // [16, scap]
    float*       __restrict__ f,        // [N,128]
    int*         __restrict__ head,     // [ncells] zeroed; stores pt+1
    int*         __restrict__ nxt,      // [N]; 0 = end-of-chain
    int n, int nblk, int scap)
{
    __shared__ float lk[CIN * COUT];    // 32 KB: kern[bin]
    __shared__ int psum[256];           // [seg][bin] partial sums (atomic-free)
    __shared__ int sc[256];             // inclusive prefix of my bin's column
    __shared__ int wsum[4];             // per-wave scan totals
    __shared__ int tot[NBINS];
    __shared__ int cbase[NBINS + 1];    // chunk-count prefix over bins

    const int tid  = threadIdx.x;
    const int wave = tid >> 6;
    const int lane = tid & 63;

    // bin totals WITHOUT LDS atomics: thread t sums rows of column (t&15);
    // then 16 threads fold 16 independent partials each.
    {
        const int bin16 = tid & 15;
        const int seg   = tid >> 4;
        const int per   = (nblk + 15) >> 4;
        const int rlo   = seg * per;
        int rhi = rlo + per; if (rhi > nblk) rhi = nblk;
        int s = 0;
        for (int vb = rlo; vb < rhi; ++vb) s += blkhist[vb * NBINS + bin16];
        psum[tid] = s;
    }
    __syncthreads();
    if (tid < NBINS) {
        int s = 0;
#pragma unroll
        for (int g = 0; g < 16; ++g) s += psum[g * 16 + tid];  // independent reads
        tot[tid] = s;
    }
    __syncthreads();
    if (tid == 0) {
        int acc = 0;
        cbase[0] = 0;
        for (int k = 0; k < NBINS; ++k) {
            acc += (tot[k] + PTS_PER_BLOCK - 1) / PTS_PER_BLOCK;
            cbase[k + 1] = acc;
        }
    }
    __syncthreads();

    const int c = blockIdx.x;
    if (c >= cbase[NBINS]) return;            // block-uniform: safe

    int bin = 0;
    while (cbase[bin + 1] <= c) ++bin;        // uniform 16-entry scan
    const int chunk = c - cbase[bin];
    const int cnt   = tot[bin];

    // inclusive prefix over my bin's per-block counts: barrier-free wave scan
    // (__shfl_up, 6 steps) + cross-wave offset fold (2 barriers total)
    {
        int v = (tid < nblk) ? blkhist[tid * NBINS + bin] : 0;
#pragma unroll
        for (int off = 1; off < 64; off <<= 1) {
            const int t = __shfl_up(v, (unsigned)off, 64);
            if (lane >= off) v += t;
        }
        if (lane == 63) wsum[wave] = v;
        __syncthreads();
        int add = 0;
#pragma unroll
        for (int w = 0; w < 3; ++w)
            if (w < wave) add += wsum[w];
        sc[tid] = v + add;
        __syncthreads();
    }

    // stage kern[bin] -> LDS (256 thr x 8 float4)
    {
        const float4* src = (const float4*)(kern + (size_t)bin * CIN * COUT);
        float4* dst = (float4*)lk;
#pragma unroll
        for (int j = 0; j < 8; ++j)
            dst[j * 256 + tid] = src[j * 256 + tid];
    }
    __syncthreads();

    const int r0 = chunk * PTS_PER_BLOCK + wave * PTS_PER_WAVE;
    const int navail = cnt - r0;
    if (navail <= 0) return;                  // no barrier after this point
    const int np = navail < PTS_PER_WAVE ? navail : PTS_PER_WAVE;

    int pts[PTS_PER_WAVE];
#pragma unroll
    for (int p = 0; p < PTS_PER_WAVE; ++p) {
        const int rr = (p < np) ? (r0 + p) : r0;   // pad tail with p0 (discarded)
        // rank -> (vb, local) via binary search on inclusive prefix (uniform)
        int lo = 0, hi = nblk;
        while (lo < hi) {
            const int mid = (lo + hi) >> 1;
            if (sc[mid] > rr) hi = mid; else lo = mid + 1;
        }
        const int local = rr - (lo ? sc[lo - 1] : 0);
        pts[p] = __builtin_amdgcn_readfirstlane(sorted[bin * scap + lo * 256 + local]);
    }

    float ax[PTS_PER_WAVE], ay[PTS_PER_WAVE];
#pragma unroll
    for (int p = 0; p < PTS_PER_WAVE; ++p) { ax[p] = 0.f; ay[p] = 0.f; }

#pragma unroll
    for (int cc = 0; cc < CIN; ++cc) {
        const float2 kv = *(const float2*)&lk[cc * COUT + 2 * lane];
#pragma unroll
        for (int p = 0; p < PTS_PER_WAVE; ++p) {
            const float fv = feats[(size_t)pts[p] * CIN + cc];  // wave-uniform -> s_load
            ax[p] = fmaf(fv, kv.x, ax[p]);
            ay[p] = fmaf(fv, kv.y, ay[p]);
        }
    }

#pragma unroll
    for (int p = 0; p < PTS_PER_WAVE; ++p) {
        if (p < np)
            *(float2*)(f + (size_t)pts[p] * COUT + 2 * lane) = make_float2(ax[p], ay[p]);
    }

    if (lane == 0) {
        const int stride = stride_p[0];
        for (int p = 0; p < np; ++p) {
            const int pt = pts[p];
            const int cx = coords[pt * 4 + 0];
            const int cz = coords[pt * 4 + 2];
            const int cb = coords[pt * 4 + 3];
            const int cell = (cb << 18) + ((cx / stride) << 9) + (cz / stride);
            const int old = atomicExch(&head[cell], pt + 1);   // lock-free push
            nxt[pt] = old;                                     // 0 = end
        }
    }
}

// ----------------- K3: R11 D4 verbatim — owner folds chain in-place into f
__global__ __launch_bounds__(256) void bev_accum(
    const int* __restrict__ coords,
    const int* __restrict__ stride_p,
    float*     __restrict__ f,          // [N,128] (in-place)
    const int* __restrict__ head,
    const int* __restrict__ nxt,
    int n)
{
    const int wave = threadIdx.x >> 6;
    const int lane = threadIdx.x & 63;
    int pt = blockIdx.x * 4 + wave;
    if (pt >= n) return;
    pt = __builtin_amdgcn_readfirstlane(pt);

    const int nx0 = __builtin_amdgcn_readfirstlane(nxt[pt]);
    if (nx0 == 0) return;                       // singleton or tail: nothing to fold

    const int stride = stride_p[0];
    const int cx = coords[pt * 4 + 0];
    const int cz = coords[pt * 4 + 2];
    const int cb = coords[pt * 4 + 3];
    const int cell = (cb << 18) + ((cx / stride) << 9) + (cz / stride);
    if (__builtin_amdgcn_readfirstlane(head[cell]) != pt + 1) return;  // owner only

    float2 acc = *(const float2*)(f + (size_t)pt * COUT + 2 * lane);
    int p = nx0;
    while (p) {                                 // disjoint chains: no hazards
        const float2 v = *(const float2*)(f + (size_t)(p - 1) * COUT + 2 * lane);
        acc.x += v.x; acc.y += v.y;
        p = __builtin_amdgcn_readfirstlane(nxt[p - 1]);
    }
    *(float2*)(f + (size_t)pt * COUT + 2 * lane) = acc;
}

// ------------- K4: o-grouped dense — block = (b, x, og16); wave owns 4 o's.
// One int4 head read per segment (reused across 4 rows); one scattered
// float4 f load per occupied cell (4 waves consume the full 64B line);
// register transpose; 4 coalesced float4 stores.
__global__ __launch_bounds__(256) void bev_dense_o16(
    const float* __restrict__ f,        // [N,128] (owner rows hold cell sums)
    const int*   __restrict__ head,     // [ncells], pt+1 or 0
    float*       __restrict__ out)      // [B,128,512,512]
{
    const int bid  = blockIdx.x;        // bid = ((b*512)+x)*8 + og
    const int wave = threadIdx.x >> 6;
    const int lane = threadIdx.x & 63;
    const int og = bid & 7;
    const int x  = (bid >> 3) & 511;
    const int b  = bid >> 12;           // 512*8 = 4096 blocks per batch
    const int o0 = og * 16 + wave * 4;  // this wave's 4 output channels

    const int* hrow = head + (b << 18) + (x << 9);   // 2KB contiguous head row
    float* const obase = out + (((size_t)(b * COUT + o0)) << 18) + ((size_t)x << 9);

#pragma unroll
    for (int h = 0; h < 2; ++h) {
        const int z = h * 256 + lane * 4;
        const int4 h4 = *(const int4*)(hrow + z);    // coalesced 1KB/wave
        float4 c0 = make_float4(0.f, 0.f, 0.f, 0.f);
        float4 c1 = c0, c2 = c0, c3 = c0;
        // one 16B scattered load per occupied cell (exec-masked, branch-free)
        if (h4.x) c0 = *(const float4*)(f + (size_t)(h4.x - 1) * COUT + o0);
        if (h4.y) c1 = *(const float4*)(f + (size_t)(h4.y - 1) * COUT + o0);
        if (h4.z) c2 = *(const float4*)(f + (size_t)(h4.z - 1) * COUT + o0);
        if (h4.w) c3 = *(const float4*)(f + (size_t)(h4.w - 1) * COUT + o0);
        // transpose: output row j takes component j of each cell
        *(float4*)(obase + ((size_t)0 << 18) + z) = make_float4(c0.x, c1.x, c2.x, c3.x);
        *(float4*)(obase + ((size_t)1 << 18) + z) = make_float4(c0.y, c1.y, c2.y, c3.y);
        *(float4*)(obase + ((size_t)2 << 18) + z) = make_float4(c0.z, c1.z, c2.z, c3.z);
        *(float4*)(obase + ((size_t)3 << 18) + z) = make_float4(c0.w, c1.w, c2.w, c3.w);
    }
}

// ------------------------------------------------------------------- launch
extern "C" void kernel_launch(void* const* d_in, const int* in_sizes, int n_in,
                              void* d_out, int out_size, void* d_ws, size_t ws_size,
                              hipStream_t stream) {
    const int*   coords   = (const int*)d_in[0];
    const float* feats    = (const float*)d_in[1];
    const float* kern     = (const float*)d_in[2];
    const int*   stride_p = (const int*)d_in[3];
    float* out = (float*)d_out;

    const int n      = in_sizes[0] / 4;      // coords is [N,4]
    const int ncells = out_size / COUT;      // B*H*W = 524288
    const int batch  = out_size / (COUT * HW);
    const int nblk   = (n + 255) / 256;      // sort blocks (157; must be <=256)
    const int scap   = nblk * 256;           // per-bin segment capacity

    // Workspace: f | head | nxt | blkhist | sorted   (nothing needs memset)
    size_t off = 0;
    float* f      = (float*)((char*)d_ws + off); off += (size_t)n * COUT * sizeof(float);
    int* head     = (int*)((char*)d_ws + off);   off += (size_t)ncells * sizeof(int);
    int* nxt      = (int*)((char*)d_ws + off);   off += (size_t)n * sizeof(int);
    int* blkhist  = (int*)((char*)d_ws + off);   off += (size_t)nblk * NBINS * sizeof(int);
    int* sorted   = (int*)((char*)d_ws + off);   off += (size_t)NBINS * scap * sizeof(int);

    // K1: zero head + bucket (head zeroing ordered before K2 by dispatch order)
    bev_sort<<<nblk, 256, 0, stream>>>(coords, stride_p, head, blkhist, sorted,
                                       n, nblk, scap, ncells);

    // K2: exact chunk count (worst case: every bin has a remainder chunk)
    const int max_chunks = (n + PTS_PER_BLOCK - 1) / PTS_PER_BLOCK + NBINS;
    bev_point<<<max_chunks, 256, 0, stream>>>(coords, feats, kern, stride_p,
                                              blkhist, sorted, f, head, nxt,
                                              n, nblk, scap);

    // K3: owner folds collision chains (R11 D4)
    bev_accum<<<(n + 3) / 4, 256, 0, stream>>>(coords, stride_p, f, head, nxt, n);

    // K4: o-grouped dense output
    const int ndblocks = batch * BEVH * 8;   // (b, x, og16) = 8192
    bev_dense_o16<<<ndblocks, 256, 0, stream>>>(f, head, out);
}